// Round 2
// baseline (1432.057 us; speedup 1.0000x reference)
//
#include <hip/hip_runtime.h>

// SignedGCN on MI355X. Pull-style aggregation via on-device CSR build.
// Edges arrive as int32 (harness converts all integers to int32).

__global__ void count_kernel(const int* __restrict__ pei, const int* __restrict__ nei,
                             int* __restrict__ cnt_p, int* __restrict__ cnt_n, int e) {
  int i = blockIdx.x * blockDim.x + threadIdx.x;
  if (i < e) {
    atomicAdd(&cnt_p[pei[e + i]], 1);
  } else if (i < 2 * e) {
    atomicAdd(&cnt_n[nei[e + (i - e)]], 1);
  }
}

// Exclusive offsets via wave-level scan + one atomic bump per wave per graph.
// Ordering across waves is arbitrary — only disjoint contiguous ranges matter.
__global__ void alloc_kernel(const int* __restrict__ cnt_p, const int* __restrict__ cnt_n,
                             int* __restrict__ off_p, int* __restrict__ off_n,
                             int* __restrict__ cur_p, int* __restrict__ cur_n,
                             int* __restrict__ tots, int n) {
  int v = blockIdx.x * blockDim.x + threadIdx.x;
  int lane = threadIdx.x & 63;
  int vp = (v < n) ? cnt_p[v] : 0;
  int vn = (v < n) ? cnt_n[v] : 0;
  int sp = vp, sn = vn;
  #pragma unroll
  for (int d = 1; d < 64; d <<= 1) {
    int tp = __shfl_up(sp, d);
    int tn = __shfl_up(sn, d);
    if (lane >= d) { sp += tp; sn += tn; }
  }
  int basep = 0, basen = 0;
  if (lane == 63) {
    basep = atomicAdd(&tots[0], sp);
    basen = atomicAdd(&tots[1], sn);
  }
  basep = __shfl(basep, 63);
  basen = __shfl(basen, 63);
  if (v < n) {
    int op = basep + sp - vp;
    int on = basen + sn - vn;
    off_p[v] = op; cur_p[v] = op;
    off_n[v] = on; cur_n[v] = on;
  }
}

__global__ void fill_kernel(const int* __restrict__ pei, const int* __restrict__ nei,
                            int* __restrict__ cur_p, int* __restrict__ cur_n,
                            int* __restrict__ list_p, int* __restrict__ list_n, int e) {
  int i = blockIdx.x * blockDim.x + threadIdx.x;
  if (i < e) {
    int dst = pei[e + i];
    int p = atomicAdd(&cur_p[dst], 1);
    list_p[p] = pei[i];
  } else if (i < 2 * e) {
    int j = i - e;
    int dst = nei[e + j];
    int p = atomicAdd(&cur_n[dst], 1);
    list_n[p] = nei[j];
  }
}

// Layer-1 aggregation: wave per (node, graph); lane = channel (64 ch).
__global__ void agg1_kernel(const float* __restrict__ x,
                            const int* __restrict__ off_p, const int* __restrict__ cnt_p, const int* __restrict__ list_p,
                            const int* __restrict__ off_n, const int* __restrict__ cnt_n, const int* __restrict__ list_n,
                            float* __restrict__ Mp, float* __restrict__ Mn, int n) {
  int wid = (blockIdx.x * blockDim.x + threadIdx.x) >> 6;
  int lane = threadIdx.x & 63;
  int v = wid >> 1;
  if (v >= n) return;
  int g = wid & 1;
  const int* off = g ? off_n : off_p;
  const int* cnt = g ? cnt_n : cnt_p;
  const int* lst = g ? list_n : list_p;
  float* M = g ? Mn : Mp;
  int d = cnt[v], o = off[v];
  float acc = 0.f;
  int i = 0;
  for (; i + 4 <= d; i += 4) {
    int s0 = lst[o + i], s1 = lst[o + i + 1], s2 = lst[o + i + 2], s3 = lst[o + i + 3];
    acc += x[(size_t)s0 * 64 + lane];
    acc += x[(size_t)s1 * 64 + lane];
    acc += x[(size_t)s2 * 64 + lane];
    acc += x[(size_t)s3 * 64 + lane];
  }
  for (; i < d; ++i) acc += x[(size_t)lst[o + i] * 64 + lane];
  M[(size_t)v * 64 + lane] = acc / (float)(d > 0 ? d : 1);
}

// Layer-2 aggregation over z (128 ch): wave per (node, graph, half64).
__global__ void agg2_kernel(const float* __restrict__ z,
                            const int* __restrict__ off_p, const int* __restrict__ cnt_p, const int* __restrict__ list_p,
                            const int* __restrict__ off_n, const int* __restrict__ cnt_n, const int* __restrict__ list_n,
                            float* __restrict__ Ap, float* __restrict__ An, int n) {
  int wid = (blockIdx.x * blockDim.x + threadIdx.x) >> 6;
  int lane = threadIdx.x & 63;
  int v = wid >> 2;
  if (v >= n) return;
  int g = (wid >> 1) & 1;
  int h = wid & 1;
  const int* off = g ? off_n : off_p;
  const int* cnt = g ? cnt_n : cnt_p;
  const int* lst = g ? list_n : list_p;
  float* A = g ? An : Ap;
  int d = cnt[v], o = off[v];
  int c = h * 64 + lane;
  float acc = 0.f;
  int i = 0;
  for (; i + 4 <= d; i += 4) {
    int s0 = lst[o + i], s1 = lst[o + i + 1], s2 = lst[o + i + 2], s3 = lst[o + i + 3];
    acc += z[(size_t)s0 * 128 + c];
    acc += z[(size_t)s1 * 128 + c];
    acc += z[(size_t)s2 * 128 + c];
    acc += z[(size_t)s3 * 128 + c];
  }
  for (; i < d; ++i) acc += z[(size_t)lst[o + i] * 128 + c];
  A[(size_t)v * 128 + c] = acc / (float)(d > 0 ? d : 1);
}

// z[:, half*64 + jj] = relu([M, x] @ W.T + b); blockIdx.y selects half (p/n).
__global__ __launch_bounds__(1024) void lin1_kernel(
    const float* __restrict__ x, const float* __restrict__ Mp, const float* __restrict__ Mn,
    const float* __restrict__ Wp1, const float* __restrict__ bp1,
    const float* __restrict__ Wn1, const float* __restrict__ bn1,
    float* __restrict__ z, int n) {
  __shared__ float Wt[128 * 64];  // Wt[k][j] = W[j][k], 32 KiB
  int half = blockIdx.y;
  const float* W  = half ? Wn1 : Wp1;
  const float* bb = half ? bn1 : bp1;
  const float* M  = half ? Mn : Mp;
  for (int f = threadIdx.x; f < 128 * 64; f += 1024) {
    int k = f >> 6, j = f & 63;
    Wt[f] = W[j * 128 + k];
  }
  __syncthreads();
  int total = n * 64;
  for (int base = blockIdx.x * 1024; base < total; base += gridDim.x * 1024) {
    int idx = base + threadIdx.x;
    if (idx < total) {
      int v = idx >> 6, jj = idx & 63;
      float acc = bb[jj];
      const float4* m4 = (const float4*)(M + (size_t)v * 64);
      const float4* x4 = (const float4*)(x + (size_t)v * 64);
      #pragma unroll
      for (int k4 = 0; k4 < 16; ++k4) {
        float4 mv = m4[k4];
        acc += mv.x * Wt[(k4 * 4 + 0) * 64 + jj];
        acc += mv.y * Wt[(k4 * 4 + 1) * 64 + jj];
        acc += mv.z * Wt[(k4 * 4 + 2) * 64 + jj];
        acc += mv.w * Wt[(k4 * 4 + 3) * 64 + jj];
      }
      #pragma unroll
      for (int k4 = 0; k4 < 16; ++k4) {
        float4 xv = x4[k4];
        acc += xv.x * Wt[(64 + k4 * 4 + 0) * 64 + jj];
        acc += xv.y * Wt[(64 + k4 * 4 + 1) * 64 + jj];
        acc += xv.z * Wt[(64 + k4 * 4 + 2) * 64 + jj];
        acc += xv.w * Wt[(64 + k4 * 4 + 3) * 64 + jj];
      }
      z[(size_t)v * 128 + half * 64 + jj] = fmaxf(acc, 0.f);
    }
  }
}

// out[:, half*64+jj] = relu([A1, A2, Zr] @ W.T + b)
__global__ __launch_bounds__(1024) void lin2_kernel(
    const float* __restrict__ z, const float* __restrict__ Ap, const float* __restrict__ An,
    const float* __restrict__ Wp2, const float* __restrict__ bp2,
    const float* __restrict__ Wn2, const float* __restrict__ bn2,
    float* __restrict__ out, int n) {
  __shared__ float Wt[192 * 64];  // 48 KiB
  int half = blockIdx.y;
  const float* W  = half ? Wn2 : Wp2;
  const float* bb = half ? bn2 : bp2;
  for (int f = threadIdx.x; f < 192 * 64; f += 1024) {
    int k = f >> 6, j = f & 63;
    Wt[f] = W[j * 192 + k];
  }
  __syncthreads();
  int total = n * 64;
  for (int base = blockIdx.x * 1024; base < total; base += gridDim.x * 1024) {
    int idx = base + threadIdx.x;
    if (idx < total) {
      int v = idx >> 6, jj = idx & 63;
      // p-half: [pp, pn, zp] = [Ap[:, :64], An[:, 64:], z[:, :64]]
      // n-half: [np, nn, zn] = [Ap[:, 64:], An[:, :64], z[:, 64:]]
      const float* A1 = half ? (Ap + (size_t)v * 128 + 64) : (Ap + (size_t)v * 128);
      const float* A2 = half ? (An + (size_t)v * 128)      : (An + (size_t)v * 128 + 64);
      const float* Zr = half ? (z  + (size_t)v * 128 + 64) : (z  + (size_t)v * 128);
      float acc = bb[jj];
      const float4* a1 = (const float4*)A1;
      const float4* a2 = (const float4*)A2;
      const float4* zr = (const float4*)Zr;
      #pragma unroll
      for (int k4 = 0; k4 < 16; ++k4) {
        float4 v1 = a1[k4];
        acc += v1.x * Wt[(k4 * 4 + 0) * 64 + jj];
        acc += v1.y * Wt[(k4 * 4 + 1) * 64 + jj];
        acc += v1.z * Wt[(k4 * 4 + 2) * 64 + jj];
        acc += v1.w * Wt[(k4 * 4 + 3) * 64 + jj];
      }
      #pragma unroll
      for (int k4 = 0; k4 < 16; ++k4) {
        float4 v2 = a2[k4];
        acc += v2.x * Wt[(64 + k4 * 4 + 0) * 64 + jj];
        acc += v2.y * Wt[(64 + k4 * 4 + 1) * 64 + jj];
        acc += v2.z * Wt[(64 + k4 * 4 + 2) * 64 + jj];
        acc += v2.w * Wt[(64 + k4 * 4 + 3) * 64 + jj];
      }
      #pragma unroll
      for (int k4 = 0; k4 < 16; ++k4) {
        float4 vz = zr[k4];
        acc += vz.x * Wt[(128 + k4 * 4 + 0) * 64 + jj];
        acc += vz.y * Wt[(128 + k4 * 4 + 1) * 64 + jj];
        acc += vz.z * Wt[(128 + k4 * 4 + 2) * 64 + jj];
        acc += vz.w * Wt[(128 + k4 * 4 + 3) * 64 + jj];
      }
      out[(size_t)v * 128 + half * 64 + jj] = fmaxf(acc, 0.f);
    }
  }
}

extern "C" void kernel_launch(void* const* d_in, const int* in_sizes, int n_in,
                              void* d_out, int out_size, void* d_ws, size_t ws_size,
                              hipStream_t stream) {
  const float* x   = (const float*)d_in[0];
  const int*   pei = (const int*)d_in[1];
  const int*   nei = (const int*)d_in[2];
  const float* Wp1 = (const float*)d_in[3];
  const float* bp1 = (const float*)d_in[4];
  const float* Wn1 = (const float*)d_in[5];
  const float* bn1 = (const float*)d_in[6];
  const float* Wp2 = (const float*)d_in[7];
  const float* bp2 = (const float*)d_in[8];
  const float* Wn2 = (const float*)d_in[9];
  const float* bn2 = (const float*)d_in[10];
  float* out = (float*)d_out;

  const int n = in_sizes[0] / 64;   // 100000
  const int e = in_sizes[1] / 2;    // 1600000

  char* w = (char*)d_ws;
  size_t off = 0;
  auto take = [&](size_t bytes) -> void* {
    void* p = (void*)(w + off);
    off += (bytes + 255) & ~(size_t)255;
    return p;
  };
  int* cnt_p  = (int*)take((size_t)n * 4);
  int* cnt_n  = (int*)take((size_t)n * 4);
  int* tots   = (int*)take(8);
  int* off_p  = (int*)take((size_t)n * 4);
  int* off_n  = (int*)take((size_t)n * 4);
  int* cur_p  = (int*)take((size_t)n * 4);
  int* cur_n  = (int*)take((size_t)n * 4);
  int* list_p = (int*)take((size_t)e * 4);
  int* list_n = (int*)take((size_t)e * 4);
  float* Mp = (float*)take((size_t)n * 64 * 4);   // n*64*4 is 256B-multiple => Mn contiguous
  float* Mn = (float*)take((size_t)n * 64 * 4);
  float* z  = (float*)take((size_t)n * 128 * 4);
  float* An = (float*)take((size_t)n * 128 * 4);
  float* Ap = Mp;  // alias: Mp/Mn are dead after lin1; Ap spans both (n*128 floats)

  hipMemsetAsync(cnt_p, 0, (size_t)n * 4, stream);
  hipMemsetAsync(cnt_n, 0, (size_t)n * 4, stream);
  hipMemsetAsync(tots, 0, 8, stream);

  int blkE = (2 * e + 255) / 256;
  count_kernel<<<blkE, 256, 0, stream>>>(pei, nei, cnt_p, cnt_n, e);
  alloc_kernel<<<(n + 255) / 256, 256, 0, stream>>>(cnt_p, cnt_n, off_p, off_n, cur_p, cur_n, tots, n);
  fill_kernel<<<blkE, 256, 0, stream>>>(pei, nei, cur_p, cur_n, list_p, list_n, e);

  // layer 1
  agg1_kernel<<<(2 * n * 64 + 255) / 256, 256, 0, stream>>>(
      x, off_p, cnt_p, list_p, off_n, cnt_n, list_n, Mp, Mn, n);
  dim3 g1(640, 2);
  lin1_kernel<<<g1, 1024, 0, stream>>>(x, Mp, Mn, Wp1, bp1, Wn1, bn1, z, n);

  // layer 2
  agg2_kernel<<<(4 * n * 64 + 255) / 256, 256, 0, stream>>>(
      z, off_p, cnt_p, list_p, off_n, cnt_n, list_n, Ap, An, n);
  lin2_kernel<<<g1, 1024, 0, stream>>>(z, Ap, An, Wp2, bp2, Wn2, bn2, out, n);
}